// Round 15
// baseline (295.864 us; speedup 1.0000x reference)
//
#include <hip/hip_runtime.h>
#include <hip/hip_bf16.h>

typedef __hip_bfloat16 bf16;
typedef __attribute__((ext_vector_type(8))) short short8b;   // 8 bf16 (MFMA operand)
typedef __attribute__((ext_vector_type(4))) float f32x4;     // MFMA accumulator

#define BB  8
#define NN  384
#define HH  12
#define HSZ 768
#define DD  64
#define PHH 64
#define PSTR 386   // pLNT row stride in u32 words
#define SWS  194   // sw row stride in u32 words

__device__ __forceinline__ float bflo(unsigned u){ union{unsigned q; float f;} c; c.q = u << 16;        return c.f; }
__device__ __forceinline__ float bfhi(unsigned u){ union{unsigned q; float f;} c; c.q = u & 0xffff0000u; return c.f; }

// pack two f32 into a u32 of two RNE-rounded bf16 (lo, hi)
__device__ __forceinline__ unsigned pk2bf(float lo, float hi){
    union{float f; unsigned u;} a, b; a.f = lo; b.f = hi;
    unsigned ua = a.u + 0x7fffu + ((a.u >> 16) & 1u);
    unsigned ub = b.u + 0x7fffu + ((b.u >> 16) & 1u);
    return (ua >> 16) | (ub & 0xffff0000u);
}

union U8 { uint4 u; short8b v; };

// pack 8 consecutive float4 (32 f32) into 4 uint4 (16 bf16-pair words)
__device__ __forceinline__ void pk32(const float4* p, uint4* o){
    #pragma unroll
    for (int e = 0; e < 4; e++) {
        float4 x = p[2*e], y = p[2*e+1];
        o[e].x = pk2bf(x.x, x.y); o[e].y = pk2bf(x.z, x.w);
        o[e].z = pk2bf(y.x, y.y); o[e].w = pk2bf(y.z, y.w);
    }
}

// ---------------------------------------------------------------------------
// K1: QKV projection, MFMA bf16.  (validated R6/R7)
// ---------------------------------------------------------------------------
__global__ __launch_bounds__(256) void k_qkv(
    const float* __restrict__ nodes,
    const float* __restrict__ Wq, const float* __restrict__ bq,
    const float* __restrict__ Wk, const float* __restrict__ bk,
    const float* __restrict__ Wv, const float* __restrict__ bv,
    float* __restrict__ oq, float* __restrict__ okk, float* __restrict__ ov)
{
    const int which = blockIdx.z;
    const float* __restrict__ W   = which==0 ? Wq : (which==1 ? Wk : Wv);
    const float* __restrict__ bia = which==0 ? bq : (which==1 ? bk : bv);
    float* __restrict__ out       = which==0 ? oq : (which==1 ? okk : ov);
    const float scale = which==0 ? 0.125f : 1.0f;

    __shared__ __align__(16) unsigned Alds[128*20];
    __shared__ __align__(16) unsigned Blds[128*20];

    const int row0 = blockIdx.x * 128;
    const int col0 = blockIdx.y * 128;
    const int tid  = threadIdx.x;
    const int wv   = tid >> 6, lane = tid & 63;
    const int wm   = wv & 1,  wn   = wv >> 1;
    const int fr   = lane & 15, kg = lane >> 4;

    f32x4 acc[4][4];
    #pragma unroll
    for (int i=0;i<4;i++){
        #pragma unroll
        for (int j=0;j<4;j++){ acc[i][j][0]=0.f; acc[i][j][1]=0.f; acc[i][j][2]=0.f; acc[i][j][3]=0.f; }
    }

    for (int k0 = 0; k0 < HSZ; k0 += 32) {
        {   // stage A: row m, k-half kh (16 f32 -> 8 words)
            const int m = tid >> 1, kh = tid & 1;
            const float4* ap = reinterpret_cast<const float4*>(nodes + (size_t)(row0 + m)*HSZ + k0 + kh*16);
            float4 a0 = ap[0], a1 = ap[1], a2 = ap[2], a3 = ap[3];
            uint4 p0, p1;
            p0.x = pk2bf(a0.x,a0.y); p0.y = pk2bf(a0.z,a0.w);
            p0.z = pk2bf(a1.x,a1.y); p0.w = pk2bf(a1.z,a1.w);
            p1.x = pk2bf(a2.x,a2.y); p1.y = pk2bf(a2.z,a2.w);
            p1.z = pk2bf(a3.x,a3.y); p1.w = pk2bf(a3.z,a3.w);
            *reinterpret_cast<uint4*>(&Alds[m*20 + kh*8    ]) = p0;
            *reinterpret_cast<uint4*>(&Alds[m*20 + kh*8 + 4]) = p1;
        }
        {   // stage B (column reads of W)
            const int n = tid & 127, kq = tid >> 7;
            const float* wp = W + (size_t)(k0 + kq*16)*HSZ + col0 + n;
            float x[16];
            #pragma unroll
            for (int j = 0; j < 16; j++) x[j] = wp[(size_t)j*HSZ];
            uint4 p0, p1;
            p0.x = pk2bf(x[0],x[1]);   p0.y = pk2bf(x[2],x[3]);
            p0.z = pk2bf(x[4],x[5]);   p0.w = pk2bf(x[6],x[7]);
            p1.x = pk2bf(x[8],x[9]);   p1.y = pk2bf(x[10],x[11]);
            p1.z = pk2bf(x[12],x[13]); p1.w = pk2bf(x[14],x[15]);
            *reinterpret_cast<uint4*>(&Blds[n*20 + kq*8    ]) = p0;
            *reinterpret_cast<uint4*>(&Blds[n*20 + kq*8 + 4]) = p1;
        }
        __syncthreads();
        U8 au[4], bu[4];
        #pragma unroll
        for (int t = 0; t < 4; t++) {
            au[t].u = *reinterpret_cast<const uint4*>(&Alds[(wm*64 + t*16 + fr)*20 + kg*4]);
            bu[t].u = *reinterpret_cast<const uint4*>(&Blds[(wn*64 + t*16 + fr)*20 + kg*4]);
        }
        #pragma unroll
        for (int mt = 0; mt < 4; mt++)
            #pragma unroll
            for (int nt = 0; nt < 4; nt++)
                acc[mt][nt] = __builtin_amdgcn_mfma_f32_16x16x32_bf16(
                    au[mt].v, bu[nt].v, acc[mt][nt], 0, 0, 0);
        __syncthreads();
    }
    #pragma unroll
    for (int nt = 0; nt < 4; nt++) {
        const int col = col0 + wn*64 + nt*16 + fr;
        const int h = col >> 6, d = col & 63;
        const float bv_ = bia[col];
        #pragma unroll
        for (int mt = 0; mt < 4; mt++) {
            #pragma unroll
            for (int r = 0; r < 4; r++) {
                const int m = row0 + wm*64 + mt*16 + kg*4 + r;
                const int b_ = m / NN, n_ = m % NN;
                out[(((size_t)b_*HH + h)*NN + n_)*DD + d] = (acc[mt][nt][r] + bv_) * scale;
            }
        }
    }
}

// ---------------------------------------------------------------------------
// K1b: qsk = q_s @ Wsk^T, MFMA.  (validated R11)
// ---------------------------------------------------------------------------
__global__ __launch_bounds__(256) void k_qsk(
    const float* __restrict__ q_s, const float* __restrict__ Wsk,
    float* __restrict__ qsk)
{
    __shared__ __align__(16) unsigned Alds[128*36];
    __shared__ __align__(16) unsigned Blds[64*36];
    const int row0 = blockIdx.x * 128;
    const int tid = threadIdx.x;
    const int wv = tid >> 6, lane = tid & 63;
    const int fr = lane & 15, kg = lane >> 4;

    {   // stage A
        const int m = tid >> 1, kh = tid & 1;
        const float4* ap = reinterpret_cast<const float4*>(q_s + (size_t)(row0 + m)*DD + kh*32);
        uint4 pa[4]; pk32(ap, pa);
        #pragma unroll
        for (int e = 0; e < 4; e++)
            *reinterpret_cast<uint4*>(&Alds[m*36 + kh*16 + 4*e]) = pa[e];
    }
    {   // stage B: Wsk rows
        const int n = tid & 63, kq = tid >> 6;
        const float4* bp = reinterpret_cast<const float4*>(Wsk + (size_t)n*DD + kq*16);
        float4 b0 = bp[0], b1 = bp[1], b2 = bp[2], b3 = bp[3];
        uint4 p0, p1;
        p0.x = pk2bf(b0.x,b0.y); p0.y = pk2bf(b0.z,b0.w);
        p0.z = pk2bf(b1.x,b1.y); p0.w = pk2bf(b1.z,b1.w);
        p1.x = pk2bf(b2.x,b2.y); p1.y = pk2bf(b2.z,b2.w);
        p1.z = pk2bf(b3.x,b3.y); p1.w = pk2bf(b3.z,b3.w);
        *reinterpret_cast<uint4*>(&Blds[n*36 + kq*8    ]) = p0;
        *reinterpret_cast<uint4*>(&Blds[n*36 + kq*8 + 4]) = p1;
    }
    __syncthreads();

    f32x4 acc[2][4];
    #pragma unroll
    for (int i=0;i<2;i++){
        #pragma unroll
        for (int j=0;j<4;j++){ acc[i][j][0]=0.f; acc[i][j][1]=0.f; acc[i][j][2]=0.f; acc[i][j][3]=0.f; }
    }
    #pragma unroll
    for (int ks = 0; ks < 2; ks++) {
        U8 au[2], bu[4];
        #pragma unroll
        for (int mt = 0; mt < 2; mt++)
            au[mt].u = *reinterpret_cast<const uint4*>(&Alds[(wv*32 + mt*16 + fr)*36 + ks*16 + kg*4]);
        #pragma unroll
        for (int nt = 0; nt < 4; nt++)
            bu[nt].u = *reinterpret_cast<const uint4*>(&Blds[(nt*16 + fr)*36 + ks*16 + kg*4]);
        #pragma unroll
        for (int mt = 0; mt < 2; mt++)
            #pragma unroll
            for (int nt = 0; nt < 4; nt++)
                acc[mt][nt] = __builtin_amdgcn_mfma_f32_16x16x32_bf16(
                    au[mt].v, bu[nt].v, acc[mt][nt], 0, 0, 0);
    }
    #pragma unroll
    for (int nt = 0; nt < 4; nt++) {
        #pragma unroll
        for (int mt = 0; mt < 2; mt++) {
            #pragma unroll
            for (int r = 0; r < 4; r++) {
                const int m = row0 + wv*32 + mt*16 + kg*4 + r;
                qsk[(size_t)m*DD + nt*16 + fr] = acc[mt][nt][r];
            }
        }
    }
}

// ---------------------------------------------------------------------------
// K2: content scores, MFMA bf16, f32 wc output.  (validated R9/R11)
// ---------------------------------------------------------------------------
__global__ __launch_bounds__(256) void k_scores(
    const float* __restrict__ q_s, const float* __restrict__ kk_, float* __restrict__ wc)
{
    const int bh = blockIdx.z;
    __shared__ __align__(16) unsigned Alds[128*36];
    __shared__ __align__(16) unsigned Blds[128*36];
    const int i0 = blockIdx.x * 128, j0 = blockIdx.y * 128;
    const int tid = threadIdx.x;
    const int wv  = tid >> 6, lane = tid & 63;
    const int wm  = wv & 1,  wn   = wv >> 1;
    const int fr  = lane & 15, kg = lane >> 4;

    {   // stage: row m = tid>>1, half kh = tid&1 -> 32 f32 = 16 words each
        const int m = tid >> 1, kh = tid & 1;
        const float4* ap = reinterpret_cast<const float4*>(q_s + ((size_t)bh*NN + i0 + m)*DD + kh*32);
        const float4* bp = reinterpret_cast<const float4*>(kk_ + ((size_t)bh*NN + j0 + m)*DD + kh*32);
        uint4 pa[4], pbq[4];
        pk32(ap, pa);
        pk32(bp, pbq);
        #pragma unroll
        for (int e = 0; e < 4; e++) {
            *reinterpret_cast<uint4*>(&Alds[m*36 + kh*16 + 4*e]) = pa[e];
            *reinterpret_cast<uint4*>(&Blds[m*36 + kh*16 + 4*e]) = pbq[e];
        }
    }
    __syncthreads();

    f32x4 acc[4][4];
    #pragma unroll
    for (int i=0;i<4;i++){
        #pragma unroll
        for (int j=0;j<4;j++){ acc[i][j][0]=0.f; acc[i][j][1]=0.f; acc[i][j][2]=0.f; acc[i][j][3]=0.f; }
    }
    #pragma unroll
    for (int ks = 0; ks < 2; ks++) {
        U8 au[4], bu[4];
        #pragma unroll
        for (int t = 0; t < 4; t++) {
            au[t].u = *reinterpret_cast<const uint4*>(&Alds[(wm*64 + t*16 + fr)*36 + ks*16 + kg*4]);
            bu[t].u = *reinterpret_cast<const uint4*>(&Blds[(wn*64 + t*16 + fr)*36 + ks*16 + kg*4]);
        }
        #pragma unroll
        for (int mt = 0; mt < 4; mt++)
            #pragma unroll
            for (int nt = 0; nt < 4; nt++)
                acc[mt][nt] = __builtin_amdgcn_mfma_f32_16x16x32_bf16(
                    au[mt].v, bu[nt].v, acc[mt][nt], 0, 0, 0);
    }
    #pragma unroll
    for (int nt = 0; nt < 4; nt++) {
        const int j = j0 + wn*64 + nt*16 + fr;
        #pragma unroll
        for (int mt = 0; mt < 4; mt++) {
            #pragma unroll
            for (int r = 0; r < 4; r++) {
                const int i = i0 + wm*64 + mt*16 + kg*4 + r;
                wc[((size_t)bh*NN + i)*NN + j] = acc[mt][nt][r];
            }
        }
    }
}

// ---------------------------------------------------------------------------
// K3: fused per-(b, i-pair), 384 thr, MFMA scores + pagg.
// R15: 2 i's per block; i1's paths load issued during i0's LN (x0 dead ->
// VGPR peak ~130 < 170, still 2 blocks/CU), hides under i0's compute.
// ---------------------------------------------------------------------------
__global__ __launch_bounds__(384) void k_soft(
    const float* __restrict__ paths, const float* __restrict__ bias,
    const float* __restrict__ pg, const float* __restrict__ pb,
    const float* __restrict__ wc, const float* __restrict__ qsk,
    float* __restrict__ pagg, float* __restrict__ w_out)
{
    const int blk = blockIdx.x;
    const int b   = blk / 192;
    const int i0  = (blk % 192) * 2;
    __shared__ __align__(16) unsigned pLNT[32 * PSTR];
    __shared__ __align__(16) unsigned sw32[16 * SWS];
    __shared__ __align__(16) unsigned qskA[16 * 36];
    __shared__ float redM[6][16];
    __shared__ float redS[6][16];
    __shared__ float pgf[64], pbf[64];
    const int tid  = threadIdx.x;
    const int wv   = tid >> 6, lane = tid & 63;
    const int g    = lane >> 4, c = lane & 15;
    const int jbase = wv*64 + c;

    // ---- hoists for both i's (except x1, issued later)
    float x0[64];
    {
        const float4* src = reinterpret_cast<const float4*>(
            paths + ((size_t)(b*NN + i0) * NN + tid) * PHH);
        #pragma unroll
        for (int t = 0; t < 16; t++) {
            float4 u = src[t];
            x0[4*t]=u.x; x0[4*t+1]=u.y; x0[4*t+2]=u.z; x0[4*t+3]=u.w;
        }
    }
    float biasj[4], wcv0[4][4], wcv1[4][4];
    #pragma unroll
    for (int nt = 0; nt < 4; nt++) {
        const int j = jbase + nt*16;
        biasj[nt] = bias[b*NN + j];
        #pragma unroll
        for (int r = 0; r < 4; r++) {
            const int h = g*4 + r;
            const size_t ro = ((size_t)(b*HH + h)*NN + i0)*NN + j;
            wcv0[nt][r] = (h < HH) ? wc[ro]      : 0.f;
            wcv1[nt][r] = (h < HH) ? wc[ro + NN] : 0.f;
        }
    }
    const int hA = tid >> 5, t2 = tid & 31;
    const size_t rA0 = ((size_t)(b*HH + hA)*NN + i0)*DD;
    const float qa0 = qsk[rA0 + 2*t2],      qa1 = qsk[rA0 + 2*t2 + 1];
    const float qb0 = qsk[rA0 + DD + 2*t2], qb1 = qsk[rA0 + DD + 2*t2 + 1];

    if (tid < 64) { pgf[tid] = pg[tid]; pbf[tid] = pb[tid]; }
    qskA[hA*36 + t2] = pk2bf(qa0, qa1);
    if (tid < 144) qskA[432 + tid] = 0u;
    __syncthreads();

    // ---- LN(i0) -> pLNT ; then issue i1's paths loads (pin in VGPRs)
    {
        float m0 = 0.f, m1 = 0.f;
        #pragma unroll
        for (int t = 0; t < 32; t++){ m0 += x0[2*t]; m1 += x0[2*t+1]; }
        const float m = (m0+m1)*(1.f/64.f);
        float v0 = 0.f, v1 = 0.f;
        #pragma unroll
        for (int t = 0; t < 32; t++){
            float a = x0[2*t]-m, d = x0[2*t+1]-m;
            v0 = fmaf(a,a,v0); v1 = fmaf(d,d,v1);
        }
        const float rs = rsqrtf((v0+v1)*(1.f/64.f) + 1e-5f);
        #pragma unroll
        for (int w = 0; w < 32; w++){
            const float lo = (x0[2*w  ]-m)*rs*pgf[2*w  ] + pbf[2*w  ];
            const float hi = (x0[2*w+1]-m)*rs*pgf[2*w+1] + pbf[2*w+1];
            pLNT[w*PSTR + tid] = pk2bf(lo, hi);
        }
    }
    float x1[64];
    {
        const float4* src = reinterpret_cast<const float4*>(
            paths + ((size_t)(b*NN + i0 + 1) * NN + tid) * PHH);
        #pragma unroll
        for (int t = 0; t < 16; t++) {
            float4 u = src[t];
            x1[4*t]=u.x; x1[4*t+1]=u.y; x1[4*t+2]=u.z; x1[4*t+3]=u.w;
        }
        #pragma unroll
        for (int t = 0; t < 64; t++) asm volatile("" : "+v"(x1[t]));
    }
    __syncthreads();

    // ================= i0: scores + softmax + w + pagg =================
    {
        f32x4 sc[4];
        #pragma unroll
        for (int nt=0;nt<4;nt++){ sc[nt][0]=0.f; sc[nt][1]=0.f; sc[nt][2]=0.f; sc[nt][3]=0.f; }
        #pragma unroll
        for (int kh = 0; kh < 2; kh++) {
            U8 a; a.u = *reinterpret_cast<const uint4*>(&qskA[c*36 + kh*16 + g*4]);
            #pragma unroll
            for (int nt = 0; nt < 4; nt++) {
                const unsigned* pb_ = &pLNT[(kh*16 + g*4)*PSTR + jbase + nt*16];
                uint4 bw;
                bw.x = pb_[0]; bw.y = pb_[PSTR]; bw.z = pb_[2*PSTR]; bw.w = pb_[3*PSTR];
                U8 bb; bb.u = bw;
                sc[nt] = __builtin_amdgcn_mfma_f32_16x16x32_bf16(a.v, bb.v, sc[nt], 0, 0, 0);
            }
        }
        #pragma unroll
        for (int nt = 0; nt < 4; nt++)
            #pragma unroll
            for (int r = 0; r < 4; r++)
                sc[nt][r] += wcv0[nt][r] + biasj[nt];

        float e_[4][4], inv_[4];
        {
            float mr[4];
            #pragma unroll
            for (int r = 0; r < 4; r++) {
                float m2 = fmaxf(fmaxf(sc[0][r], sc[1][r]), fmaxf(sc[2][r], sc[3][r]));
                #pragma unroll
                for (int o = 1; o <= 8; o <<= 1) m2 = fmaxf(m2, __shfl_xor(m2, o, 64));
                mr[r] = m2;
            }
            if (c == 0) {
                #pragma unroll
                for (int r = 0; r < 4; r++) redM[wv][g*4 + r] = mr[r];
            }
            __syncthreads();
            #pragma unroll
            for (int r = 0; r < 4; r++) {
                float Mv = redM[0][g*4 + r];
                #pragma unroll
                for (int w2 = 1; w2 < 6; w2++) Mv = fmaxf(Mv, redM[w2][g*4 + r]);
                float s2 = 0.f;
                #pragma unroll
                for (int nt = 0; nt < 4; nt++){ e_[nt][r] = __expf(sc[nt][r] - Mv); s2 += e_[nt][r]; }
                #pragma unroll
                for (int o = 1; o <= 8; o <<= 1) s2 += __shfl_xor(s2, o, 64);
                mr[r] = s2;
            }
            if (c == 0) {
                #pragma unroll
                for (int r = 0; r < 4; r++) redS[wv][g*4 + r] = mr[r];
            }
            __syncthreads();
            #pragma unroll
            for (int r = 0; r < 4; r++) {
                float Sv = redS[0][g*4 + r];
                #pragma unroll
                for (int w2 = 1; w2 < 6; w2++) Sv += redS[w2][g*4 + r];
                inv_[r] = 1.f / Sv;
            }
        }
        #pragma unroll
        for (int nt = 0; nt < 4; nt++) {
            const int j = jbase + nt*16;
            #pragma unroll
            for (int r = 0; r < 4; r++) {
                const int h = g*4 + r;
                const float wgt = e_[nt][r] * inv_[r];
                if (h < HH) w_out[((size_t)(b*HH + h)*NN + i0)*NN + j] = wgt;
                const float oth = __shfl_xor(wgt, 1, 64);
                if ((c & 1) == 0) sw32[h*SWS + (j >> 1)] = pk2bf(wgt, oth);
            }
        }
        __syncthreads();

        // pagg(i0) on waves 0..3; all threads also refill qskA for i1
        qskA[hA*36 + t2] = pk2bf(qb0, qb1);
        if (wv < 4) {
            f32x4 pa; pa[0]=0.f; pa[1]=0.f; pa[2]=0.f; pa[3]=0.f;
            const int prow = 8*wv + (c >> 1);
            const bool hi = (c & 1);
            #pragma unroll 4
            for (int kt = 0; kt < 12; kt++) {
                uint2 a0 = *reinterpret_cast<const uint2*>(&sw32[c*SWS + kt*16 + g*4]);
                uint2 a1 = *reinterpret_cast<const uint2*>(&sw32[c*SWS + kt*16 + g*4 + 2]);
                U8 af; af.u.x = a0.x; af.u.y = a0.y; af.u.z = a1.x; af.u.w = a1.y;
                const unsigned* pr = &pLNT[prow*PSTR + 32*kt + 8*g];
                uint2 w01 = *reinterpret_cast<const uint2*>(&pr[0]);
                uint2 w23 = *reinterpret_cast<const uint2*>(&pr[2]);
                uint2 w45 = *reinterpret_cast<const uint2*>(&pr[4]);
                uint2 w67 = *reinterpret_cast<const uint2*>(&pr[6]);
                uint4 bw;
                if (hi) {
                    bw.x = (w01.x >> 16) | (w01.y & 0xffff0000u);
                    bw.y = (w23.x >> 16) | (w23.y & 0xffff0000u);
                    bw.z = (w45.x >> 16) | (w45.y & 0xffff0000u);
                    bw.w = (w67.x >> 16) | (w67.y & 0xffff0000u);
                } else {
                    bw.x = (w01.x & 0xffffu) | (w01.y << 16);
                    bw.y = (w23.x & 0xffffu) | (w23.y << 16);
                    bw.z = (w45.x & 0xffffu) | (w45.y << 16);
                    bw.w = (w67.x & 0xffffu) | (w67.y << 16);
                }
                U8 bf_; bf_.u = bw;
                pa = __builtin_amdgcn_mfma_f32_16x16x32_bf16(af.v, bf_.v, pa, 0, 0, 0);
            }
            #pragma unroll
            for (int r = 0; r < 4; r++) {
                const int h = g*4 + r;
                if (h < HH)
                    pagg[((size_t)(b*HH + h)*NN + i0)*DD + 16*wv + c] = pa[r];
            }
        }
    }
    __syncthreads();

    // ---- LN(i1) -> pLNT (overwrite; pagg(i0) done reading)
    {
        float m0 = 0.f, m1 = 0.f;
        #pragma unroll
        for (int t = 0; t < 32; t++){ m0 += x1[2*t]; m1 += x1[2*t+1]; }
        const float m = (m0+m1)*(1.f/64.f);
        float v0 = 0.f, v1 = 0.f;
        #pragma unroll
        for (int t = 0; t < 32; t++){
            float a = x1[2*t]-m, d = x1[2*t+1]-m;
            v0 = fmaf(a,a,v0); v1 = fmaf(d,d,v1);
        }
        const float rs = rsqrtf((v0+v1)*(1.f/64.f) + 1e-5f);
        #pragma unroll
        for (int w = 0; w < 32; w++){
            const float lo = (x1[2*w  ]-m)*rs*pgf[2*w  ] + pbf[2*w  ];
            const float hi = (x1[2*w+1]-m)*rs*pgf[2*w+1] + pbf[2*w+1];
            pLNT[w*PSTR + tid] = pk2bf(lo, hi);
        }
    }
    __syncthreads();

    // ================= i1: scores + softmax + w + pagg =================
    {
        const int i1 = i0 + 1;
        f32x4 sc[4];
        #pragma unroll
        for (int nt=0;nt<4;nt++){ sc[nt][0]=0.f; sc[nt][1]=0.f; sc[nt][2]=0.f; sc[nt][3]=0.f; }
        #pragma unroll
        for (int kh = 0; kh < 2; kh++) {
            U8 a; a.u = *reinterpret_cast<const uint4*>(&qskA[c*36 + kh*16 + g*4]);
            #pragma unroll
            for (int nt = 0; nt < 4; nt++) {
                const unsigned* pb_ = &pLNT[(kh*16 + g*4)*PSTR + jbase + nt*16];
                uint4 bw;
                bw.x = pb_[0]; bw.y = pb_[PSTR]; bw.z = pb_[2*PSTR]; bw.w = pb_[3*PSTR];
                U8 bb; bb.u = bw;
                sc[nt] = __builtin_amdgcn_mfma_f32_16x16x32_bf16(a.v, bb.v, sc[nt], 0, 0, 0);
            }
        }
        #pragma unroll
        for (int nt = 0; nt < 4; nt++)
            #pragma unroll
            for (int r = 0; r < 4; r++)
                sc[nt][r] += wcv1[nt][r] + biasj[nt];

        float e_[4][4], inv_[4];
        {
            float mr[4];
            #pragma unroll
            for (int r = 0; r < 4; r++) {
                float m2 = fmaxf(fmaxf(sc[0][r], sc[1][r]), fmaxf(sc[2][r], sc[3][r]));
                #pragma unroll
                for (int o = 1; o <= 8; o <<= 1) m2 = fmaxf(m2, __shfl_xor(m2, o, 64));
                mr[r] = m2;
            }
            if (c == 0) {
                #pragma unroll
                for (int r = 0; r < 4; r++) redM[wv][g*4 + r] = mr[r];
            }
            __syncthreads();
            #pragma unroll
            for (int r = 0; r < 4; r++) {
                float Mv = redM[0][g*4 + r];
                #pragma unroll
                for (int w2 = 1; w2 < 6; w2++) Mv = fmaxf(Mv, redM[w2][g*4 + r]);
                float s2 = 0.f;
                #pragma unroll
                for (int nt = 0; nt < 4; nt++){ e_[nt][r] = __expf(sc[nt][r] - Mv); s2 += e_[nt][r]; }
                #pragma unroll
                for (int o = 1; o <= 8; o <<= 1) s2 += __shfl_xor(s2, o, 64);
                mr[r] = s2;
            }
            if (c == 0) {
                #pragma unroll
                for (int r = 0; r < 4; r++) redS[wv][g*4 + r] = mr[r];
            }
            __syncthreads();
            #pragma unroll
            for (int r = 0; r < 4; r++) {
                float Sv = redS[0][g*4 + r];
                #pragma unroll
                for (int w2 = 1; w2 < 6; w2++) Sv += redS[w2][g*4 + r];
                inv_[r] = 1.f / Sv;
            }
        }
        #pragma unroll
        for (int nt = 0; nt < 4; nt++) {
            const int j = jbase + nt*16;
            #pragma unroll
            for (int r = 0; r < 4; r++) {
                const int h = g*4 + r;
                const float wgt = e_[nt][r] * inv_[r];
                if (h < HH) w_out[((size_t)(b*HH + h)*NN + i1)*NN + j] = wgt;
                const float oth = __shfl_xor(wgt, 1, 64);
                if ((c & 1) == 0) sw32[h*SWS + (j >> 1)] = pk2bf(wgt, oth);
            }
        }
        __syncthreads();

        if (wv < 4) {
            f32x4 pa; pa[0]=0.f; pa[1]=0.f; pa[2]=0.f; pa[3]=0.f;
            const int prow = 8*wv + (c >> 1);
            const bool hi = (c & 1);
            #pragma unroll 4
            for (int kt = 0; kt < 12; kt++) {
                uint2 a0 = *reinterpret_cast<const uint2*>(&sw32[c*SWS + kt*16 + g*4]);
                uint2 a1 = *reinterpret_cast<const uint2*>(&sw32[c*SWS + kt*16 + g*4 + 2]);
                U8 af; af.u.x = a0.x; af.u.y = a0.y; af.u.z = a1.x; af.u.w = a1.y;
                const unsigned* pr = &pLNT[prow*PSTR + 32*kt + 8*g];
                uint2 w01 = *reinterpret_cast<const uint2*>(&pr[0]);
                uint2 w23 = *reinterpret_cast<const uint2*>(&pr[2]);
                uint2 w45 = *reinterpret_cast<const uint2*>(&pr[4]);
                uint2 w67 = *reinterpret_cast<const uint2*>(&pr[6]);
                uint4 bw;
                if (hi) {
                    bw.x = (w01.x >> 16) | (w01.y & 0xffff0000u);
                    bw.y = (w23.x >> 16) | (w23.y & 0xffff0000u);
                    bw.z = (w45.x >> 16) | (w45.y & 0xffff0000u);
                    bw.w = (w67.x >> 16) | (w67.y & 0xffff0000u);
                } else {
                    bw.x = (w01.x & 0xffffu) | (w01.y << 16);
                    bw.y = (w23.x & 0xffffu) | (w23.y << 16);
                    bw.z = (w45.x & 0xffffu) | (w45.y << 16);
                    bw.w = (w67.x & 0xffffu) | (w67.y << 16);
                }
                U8 bf_; bf_.u = bw;
                pa = __builtin_amdgcn_mfma_f32_16x16x32_bf16(af.v, bf_.v, pa, 0, 0, 0);
            }
            #pragma unroll
            for (int r = 0; r < 4; r++) {
                const int h = g*4 + r;
                if (h < HH)
                    pagg[((size_t)(b*HH + h)*NN + i1)*DD + 16*wv + c] = pa[r];
            }
        }
    }
}

// ---------------------------------------------------------------------------
// K4: attn = w@v + pagg@Wsv + bsv, MFMA bf16.  (validated R9/R11)
// ---------------------------------------------------------------------------
__global__ __launch_bounds__(256) void k_av(
    const float* __restrict__ w, const float* __restrict__ v_,
    const float* __restrict__ pagg, const float* __restrict__ Wsv,
    const float* __restrict__ bsv, float* __restrict__ attn)
{
    const int bh = blockIdx.y;
    const int b = bh / HH, h = bh % HH;
    const int i0 = blockIdx.x * 128;
    __shared__ __align__(16) unsigned Alds[128*36];
    __shared__ __align__(16) unsigned Blds[64*36];
    const int tid = threadIdx.x;
    const int wv  = tid >> 6, lane = tid & 63;
    const int fr  = lane & 15, kg = lane >> 4;

    f32x4 acc[2][4];
    #pragma unroll
    for (int i=0;i<2;i++){
        #pragma unroll
        for (int j=0;j<4;j++){ acc[i][j][0]=0.f; acc[i][j][1]=0.f; acc[i][j][2]=0.f; acc[i][j][3]=0.f; }
    }

    for (int step = 0; step < 7; step++) {
        const int j0 = step * 64;
        {   // stage A rows: w (steps 0-5) or pagg (step 6); 32 f32/thread
            const int m = tid >> 1, kh = tid & 1;
            const float4* ap = (step < 6)
                ? reinterpret_cast<const float4*>(w    + ((size_t)bh*NN + i0 + m)*NN  + j0 + kh*32)
                : reinterpret_cast<const float4*>(pagg + ((size_t)bh*NN + i0 + m)*PHH + kh*32);
            uint4 pa[4];
            pk32(ap, pa);
            #pragma unroll
            for (int e = 0; e < 4; e++)
                *reinterpret_cast<uint4*>(&Alds[m*36 + kh*16 + 4*e]) = pa[e];
        }
        {   // stage B^T: v (steps 0-5) or Wsv (step 6); column reads
            const int d = tid & 63, kq = tid >> 6;
            const float* vp = (step < 6)
                ? (v_  + ((size_t)bh*NN + j0 + kq*16)*DD + d)
                : (Wsv + (size_t)(kq*16)*DD + d);
            float x[16];
            #pragma unroll
            for (int t = 0; t < 16; t++) x[t] = vp[(size_t)t*DD];
            uint4 p0,p1;
            p0.x=pk2bf(x[0],x[1]);   p0.y=pk2bf(x[2],x[3]);
            p0.z=pk2bf(x[4],x[5]);   p0.w=pk2bf(x[6],x[7]);
            p1.x=pk2bf(x[8],x[9]);   p1.y=pk2bf(x[10],x[11]);
            p1.z=pk2bf(x[12],x[13]); p1.w=pk2bf(x[14],x[15]);
            *reinterpret_cast<uint4*>(&Blds[d*36 + kq*8    ]) = p0;
            *reinterpret_cast<uint4*>(&Blds[d*36 + kq*8 + 4]) = p1;
        }
        __syncthreads();
        #pragma unroll
        for (int ks = 0; ks < 2; ks++) {
            U8 au[2], bu[4];
            #pragma unroll
            for (int mt = 0; mt < 2; mt++)
                au[mt].u = *reinterpret_cast<const uint4*>(&Alds[(wv*32 + mt*16 + fr)*36 + ks*16 + kg*4]);
            #pragma unroll
            for (int nt = 0; nt < 4; nt++)
                bu[nt].u = *reinterpret_cast<const uint4*>(&Blds[(nt*16 + fr)*36 + ks*16 + kg*4]);
            #pragma unroll
            for (int mt = 0; mt < 2; mt++)
                #pragma unroll
                for (int nt = 0; nt < 4; nt++)
                    acc[mt][nt] = __builtin_amdgcn_mfma_f32_16x16x32_bf16(
                        au[mt].v, bu[nt].v, acc[mt][nt], 0, 0, 0);
        }
        __syncthreads();
    }
    #pragma unroll
    for (int nt = 0; nt < 4; nt++) {
        const int d = nt*16 + fr;
        const float bv_ = bsv[d];
        #pragma unroll
        for (int mt = 0; mt < 2; mt++) {
            #pragma unroll
            for (int r = 0; r < 4; r++) {
                const int i = i0 + wv*32 + mt*16 + kg*4 + r;
                attn[((size_t)b*NN + i)*HSZ + h*DD + d] = acc[mt][nt][r] + bv_;
            }
        }
    }
}

// ---------------------------------------------------------------------------
// K5a: tres = nodes + relu(attn @ Wo + bo)   -- MFMA (validated R7)
// ---------------------------------------------------------------------------
__global__ __launch_bounds__(256) void k_proj(
    const float* __restrict__ attn, const float* __restrict__ Wo,
    const float* __restrict__ bo, const float* __restrict__ nodes,
    float* __restrict__ tres)
{
    __shared__ __align__(16) unsigned Alds[128*20];
    __shared__ __align__(16) unsigned Blds[128*20];

    const int row0 = blockIdx.x * 128;
    const int col0 = blockIdx.y * 128;
    const int tid  = threadIdx.x;
    const int wv   = tid >> 6, lane = tid & 63;
    const int wm   = wv & 1,  wn   = wv >> 1;
    const int fr   = lane & 15, kg = lane >> 4;

    f32x4 acc[4][4];
    #pragma unroll
    for (int i=0;i<4;i++){
        #pragma unroll
        for (int j=0;j<4;j++){ acc[i][j][0]=0.f; acc[i][j][1]=0.f; acc[i][j][2]=0.f; acc[i][j][3]=0.f; }
    }

    for (int k0 = 0; k0 < HSZ; k0 += 32) {
        {
            const int m = tid >> 1, kh = tid & 1;
            const float4* ap = reinterpret_cast<const float4*>(attn + (size_t)(row0 + m)*HSZ + k0 + kh*16);
            float4 a0 = ap[0], a1 = ap[1], a2 = ap[2], a3 = ap[3];
            uint4 p0, p1;
            p0.x = pk2bf(a0.x,a0.y); p0.y = pk2bf(a0.z,a0.w);
            p0.z = pk2bf(a1.x,a1.y); p0.w = pk2bf(a1.z,a1.w);
            p1.x = pk2bf(a2.x,a2.y); p1.y = pk2bf(a2.z,a2.w);
            p1.z = pk2bf(a3.x,a3.y); p1.w = pk2bf(a3.z,a3.w);
            *reinterpret_cast<uint4*>(&Alds[m*20 + kh*8    ]) = p0;
            *reinterpret_cast<uint4*>(&Alds[m*20 + kh*8 + 4]) = p1;
        }
        {
            const int n = tid & 127, kq = tid >> 7;
            const float* wp = Wo + (size_t)(k0 + kq*16)*HSZ + col0 + n;
            float x[16];
            #pragma unroll
            for (int j = 0; j < 16; j++) x[j] = wp[(size_t)j*HSZ];
            uint4 p0, p1;
            p0.x = pk2bf(x[0],x[1]);   p0.y = pk2bf(x[2],x[3]);
            p0.z = pk2bf(x[4],x[5]);   p0.w = pk2bf(x[6],x[7]);
            p1.x = pk2bf(x[8],x[9]);   p1.y = pk2bf(x[10],x[11]);
            p1.z = pk2bf(x[12],x[13]); p1.w = pk2bf(x[14],x[15]);
            *reinterpret_cast<uint4*>(&Blds[n*20 + kq*8    ]) = p0;
            *reinterpret_cast<uint4*>(&Blds[n*20 + kq*8 + 4]) = p1;
        }
        __syncthreads();
        U8 au[4], bu[4];
        #pragma unroll
        for (int t = 0; t < 4; t++) {
            au[t].u = *reinterpret_cast<const uint4*>(&Alds[(wm*64 + t*16 + fr)*20 + kg*4]);
            bu[t].u = *reinterpret_cast<const uint4*>(&Blds[(wn*64 + t*16 + fr)*20 + kg*4]);
        }
        #pragma unroll
        for (int mt = 0; mt < 4; mt++)
            #pragma unroll
            for (int nt = 0; nt < 4; nt++)
                acc[mt][nt] = __builtin_amdgcn_mfma_f32_16x16x32_bf16(
                    au[mt].v, bu[nt].v, acc[mt][nt], 0, 0, 0);
        __syncthreads();
    }
    #pragma unroll
    for (int nt = 0; nt < 4; nt++) {
        const int col = col0 + wn*64 + nt*16 + fr;
        const float bov = bo[col];
        #pragma unroll
        for (int mt = 0; mt < 4; mt++) {
            #pragma unroll
            for (int r = 0; r < 4; r++) {
                const int m = row0 + wm*64 + mt*16 + kg*4 + r;
                const float val = fmaxf(acc[mt][nt][r] + bov, 0.f) + nodes[(size_t)m*HSZ + col];
                tres[(size_t)m*HSZ + col] = val;
            }
        }
    }
}

// ---------------------------------------------------------------------------
// K5b: row LayerNorm, 1 wave per row, 4 rows/block.  (validated R11)
// ---------------------------------------------------------------------------
__global__ __launch_bounds__(256) void k_ln(
    const float* __restrict__ tres, const float* __restrict__ g,
    const float* __restrict__ bta, float* __restrict__ out0)
{
    const int row  = blockIdx.x * 4 + (threadIdx.x >> 6);
    const int lane = threadIdx.x & 63;
    const float4* x4 = reinterpret_cast<const float4*>(tres + (size_t)row * HSZ);
    float4 v[3];
    #pragma unroll
    for (int t = 0; t < 3; t++) v[t] = x4[lane + t*64];
    float s = 0.f;
    #pragma unroll
    for (int t = 0; t < 3; t++) s += v[t].x + v[t].y + v[t].z + v[t].w;
    #pragma unroll
    for (int o = 32; o > 0; o >>= 1) s += __shfl_xor(s, o, 64);
    const float m = s * (1.f/768.f);
    float vs = 0.f;
    #pragma unroll
    for (int t = 0; t < 3; t++) {
        float a = v[t].x-m, b = v[t].y-m, c = v[t].z-m, d = v[t].w-m;
        vs += a*a + b*b + c*c + d*d;
    }
    #pragma unroll
    for (int o = 32; o > 0; o >>= 1) vs += __shfl_xor(vs, o, 64);
    const float rs = rsqrtf(vs * (1.f/768.f) + 1e-5f);
    const float4* g4 = reinterpret_cast<const float4*>(g);
    const float4* b4 = reinterpret_cast<const float4*>(bta);
    float4* o4 = reinterpret_cast<float4*>(out0 + (size_t)row * HSZ);
    #pragma unroll
    for (int t = 0; t < 3; t++) {
        const int idx = lane + t*64;
        float4 gg = g4[idx], bb = b4[idx], o;
        o.x = (v[t].x-m)*rs*gg.x + bb.x;
        o.y = (v[t].y-m)*rs*gg.y + bb.y;
        o.z = (v[t].z-m)*rs*gg.z + bb.z;
        o.w = (v[t].w-m)*rs*gg.w + bb.w;
        o4[idx] = o;
    }
}

// ---------------------------------------------------------------------------
extern "C" void kernel_launch(void* const* d_in, const int* in_sizes, int n_in,
                              void* d_out, int out_size, void* d_ws, size_t ws_size,
                              hipStream_t stream)
{
    (void)in_sizes; (void)n_in; (void)out_size; (void)ws_size;
    const float* nodes = (const float*)d_in[0];
    const float* bias  = (const float*)d_in[1];
    const float* paths = (const float*)d_in[2];
    const float* Wq = (const float*)d_in[3];
    const float* bq = (const float*)d_in[4];
    const float* Wk = (const float*)d_in[5];
    const float* bk = (const float*)d_in[6];
    const float* Wv = (const float*)d_in[7];
    const float* bv = (const float*)d_in[8];
    const float* Wsk= (const float*)d_in[9];
    const float* Wsv= (const float*)d_in[11];
    const float* bsv= (const float*)d_in[12];
    const float* Wo = (const float*)d_in[13];
    const float* bo = (const float*)d_in[14];
    const float* lng= (const float*)d_in[15];
    const float* lnb= (const float*)d_in[16];
    const float* plg= (const float*)d_in[17];
    const float* plb= (const float*)d_in[18];

    // ws layout (f32 slots), lifetime reuse (R11 layout):
    float* ws   = (float*)d_ws;
    float* q_s  = ws;
    float* kbuf = ws + 2359296;
    float* vbuf = ws + 4718592;
    float* qsk  = ws + 7077888;
    float* wc   = ws + 9474048;
    float* attn = q_s;
    float* pagg = kbuf;
    float* tres = wc;

    float* out0 = (float*)d_out;
    float* wout = out0 + (size_t)BB*NN*HSZ;

    hipLaunchKernelGGL(k_qkv,    dim3(24,6,3), dim3(256), 0, stream,
                       nodes, Wq,bq, Wk,bk, Wv,bv, q_s, kbuf, vbuf);
    hipLaunchKernelGGL(k_qsk,    dim3(288),    dim3(256), 0, stream,
                       q_s, Wsk, qsk);
    hipLaunchKernelGGL(k_scores, dim3(3,3,96), dim3(256), 0, stream,
                       q_s, kbuf, wc);
    hipLaunchKernelGGL(k_soft,   dim3(1536),   dim3(384), 0, stream,
                       paths, bias, plg, plb, wc, qsk, pagg, wout);
    hipLaunchKernelGGL(k_av,     dim3(3,96),   dim3(256), 0, stream,
                       wout, vbuf, pagg, Wsv, bsv, attn);
    hipLaunchKernelGGL(k_proj,   dim3(24,6),   dim3(256), 0, stream,
                       attn, Wo, bo, nodes, tres);
    hipLaunchKernelGGL(k_ln,     dim3(768),    dim3(256), 0, stream,
                       tres, lng, lnb, out0);
}

// Round 16
// 280.072 us; speedup vs baseline: 1.0564x; 1.0564x over previous
//
#include <hip/hip_runtime.h>
#include <hip/hip_bf16.h>

typedef __hip_bfloat16 bf16;
typedef __attribute__((ext_vector_type(8))) short short8b;   // 8 bf16 (MFMA operand)
typedef __attribute__((ext_vector_type(4))) float f32x4;     // MFMA accumulator

#define BB  8
#define NN  384
#define HH  12
#define HSZ 768
#define DD  64
#define PHH 64
#define PSTR 386   // pLNT row stride in u32 words
#define SWS  194   // sw row stride in u32 words

__device__ __forceinline__ float bflo(unsigned u){ union{unsigned q; float f;} c; c.q = u << 16;        return c.f; }
__device__ __forceinline__ float bfhi(unsigned u){ union{unsigned q; float f;} c; c.q = u & 0xffff0000u; return c.f; }

// pack two f32 into a u32 of two RNE-rounded bf16 (lo, hi)
__device__ __forceinline__ unsigned pk2bf(float lo, float hi){
    union{float f; unsigned u;} a, b; a.f = lo; b.f = hi;
    unsigned ua = a.u + 0x7fffu + ((a.u >> 16) & 1u);
    unsigned ub = b.u + 0x7fffu + ((b.u >> 16) & 1u);
    return (ua >> 16) | (ub & 0xffff0000u);
}

union U8 { uint4 u; short8b v; };

// pack 8 consecutive float4 (32 f32) into 4 uint4 (16 bf16-pair words)
__device__ __forceinline__ void pk32(const float4* p, uint4* o){
    #pragma unroll
    for (int e = 0; e < 4; e++) {
        float4 x = p[2*e], y = p[2*e+1];
        o[e].x = pk2bf(x.x, x.y); o[e].y = pk2bf(x.z, x.w);
        o[e].z = pk2bf(y.x, y.y); o[e].w = pk2bf(y.z, y.w);
    }
}

// ---------------------------------------------------------------------------
// K1: QKV projection, MFMA bf16.  (validated R6/R7)
// ---------------------------------------------------------------------------
__global__ __launch_bounds__(256) void k_qkv(
    const float* __restrict__ nodes,
    const float* __restrict__ Wq, const float* __restrict__ bq,
    const float* __restrict__ Wk, const float* __restrict__ bk,
    const float* __restrict__ Wv, const float* __restrict__ bv,
    float* __restrict__ oq, float* __restrict__ okk, float* __restrict__ ov)
{
    const int which = blockIdx.z;
    const float* __restrict__ W   = which==0 ? Wq : (which==1 ? Wk : Wv);
    const float* __restrict__ bia = which==0 ? bq : (which==1 ? bk : bv);
    float* __restrict__ out       = which==0 ? oq : (which==1 ? okk : ov);
    const float scale = which==0 ? 0.125f : 1.0f;

    __shared__ __align__(16) unsigned Alds[128*20];
    __shared__ __align__(16) unsigned Blds[128*20];

    const int row0 = blockIdx.x * 128;
    const int col0 = blockIdx.y * 128;
    const int tid  = threadIdx.x;
    const int wv   = tid >> 6, lane = tid & 63;
    const int wm   = wv & 1,  wn   = wv >> 1;
    const int fr   = lane & 15, kg = lane >> 4;

    f32x4 acc[4][4];
    #pragma unroll
    for (int i=0;i<4;i++){
        #pragma unroll
        for (int j=0;j<4;j++){ acc[i][j][0]=0.f; acc[i][j][1]=0.f; acc[i][j][2]=0.f; acc[i][j][3]=0.f; }
    }

    for (int k0 = 0; k0 < HSZ; k0 += 32) {
        {   // stage A: row m, k-half kh (16 f32 -> 8 words)
            const int m = tid >> 1, kh = tid & 1;
            const float4* ap = reinterpret_cast<const float4*>(nodes + (size_t)(row0 + m)*HSZ + k0 + kh*16);
            float4 a0 = ap[0], a1 = ap[1], a2 = ap[2], a3 = ap[3];
            uint4 p0, p1;
            p0.x = pk2bf(a0.x,a0.y); p0.y = pk2bf(a0.z,a0.w);
            p0.z = pk2bf(a1.x,a1.y); p0.w = pk2bf(a1.z,a1.w);
            p1.x = pk2bf(a2.x,a2.y); p1.y = pk2bf(a2.z,a2.w);
            p1.z = pk2bf(a3.x,a3.y); p1.w = pk2bf(a3.z,a3.w);
            *reinterpret_cast<uint4*>(&Alds[m*20 + kh*8    ]) = p0;
            *reinterpret_cast<uint4*>(&Alds[m*20 + kh*8 + 4]) = p1;
        }
        {   // stage B (column reads of W)
            const int n = tid & 127, kq = tid >> 7;
            const float* wp = W + (size_t)(k0 + kq*16)*HSZ + col0 + n;
            float x[16];
            #pragma unroll
            for (int j = 0; j < 16; j++) x[j] = wp[(size_t)j*HSZ];
            uint4 p0, p1;
            p0.x = pk2bf(x[0],x[1]);   p0.y = pk2bf(x[2],x[3]);
            p0.z = pk2bf(x[4],x[5]);   p0.w = pk2bf(x[6],x[7]);
            p1.x = pk2bf(x[8],x[9]);   p1.y = pk2bf(x[10],x[11]);
            p1.z = pk2bf(x[12],x[13]); p1.w = pk2bf(x[14],x[15]);
            *reinterpret_cast<uint4*>(&Blds[n*20 + kq*8    ]) = p0;
            *reinterpret_cast<uint4*>(&Blds[n*20 + kq*8 + 4]) = p1;
        }
        __syncthreads();
        U8 au[4], bu[4];
        #pragma unroll
        for (int t = 0; t < 4; t++) {
            au[t].u = *reinterpret_cast<const uint4*>(&Alds[(wm*64 + t*16 + fr)*20 + kg*4]);
            bu[t].u = *reinterpret_cast<const uint4*>(&Blds[(wn*64 + t*16 + fr)*20 + kg*4]);
        }
        #pragma unroll
        for (int mt = 0; mt < 4; mt++)
            #pragma unroll
            for (int nt = 0; nt < 4; nt++)
                acc[mt][nt] = __builtin_amdgcn_mfma_f32_16x16x32_bf16(
                    au[mt].v, bu[nt].v, acc[mt][nt], 0, 0, 0);
        __syncthreads();
    }
    #pragma unroll
    for (int nt = 0; nt < 4; nt++) {
        const int col = col0 + wn*64 + nt*16 + fr;
        const int h = col >> 6, d = col & 63;
        const float bv_ = bia[col];
        #pragma unroll
        for (int mt = 0; mt < 4; mt++) {
            #pragma unroll
            for (int r = 0; r < 4; r++) {
                const int m = row0 + wm*64 + mt*16 + kg*4 + r;
                const int b_ = m / NN, n_ = m % NN;
                out[(((size_t)b_*HH + h)*NN + n_)*DD + d] = (acc[mt][nt][r] + bv_) * scale;
            }
        }
    }
}

// ---------------------------------------------------------------------------
// K1b: qsk = q_s @ Wsk^T, MFMA.  (validated R11)
// ---------------------------------------------------------------------------
__global__ __launch_bounds__(256) void k_qsk(
    const float* __restrict__ q_s, const float* __restrict__ Wsk,
    float* __restrict__ qsk)
{
    __shared__ __align__(16) unsigned Alds[128*36];
    __shared__ __align__(16) unsigned Blds[64*36];
    const int row0 = blockIdx.x * 128;
    const int tid = threadIdx.x;
    const int wv = tid >> 6, lane = tid & 63;
    const int fr = lane & 15, kg = lane >> 4;

    {   // stage A
        const int m = tid >> 1, kh = tid & 1;
        const float4* ap = reinterpret_cast<const float4*>(q_s + (size_t)(row0 + m)*DD + kh*32);
        uint4 pa[4]; pk32(ap, pa);
        #pragma unroll
        for (int e = 0; e < 4; e++)
            *reinterpret_cast<uint4*>(&Alds[m*36 + kh*16 + 4*e]) = pa[e];
    }
    {   // stage B: Wsk rows
        const int n = tid & 63, kq = tid >> 6;
        const float4* bp = reinterpret_cast<const float4*>(Wsk + (size_t)n*DD + kq*16);
        float4 b0 = bp[0], b1 = bp[1], b2 = bp[2], b3 = bp[3];
        uint4 p0, p1;
        p0.x = pk2bf(b0.x,b0.y); p0.y = pk2bf(b0.z,b0.w);
        p0.z = pk2bf(b1.x,b1.y); p0.w = pk2bf(b1.z,b1.w);
        p1.x = pk2bf(b2.x,b2.y); p1.y = pk2bf(b2.z,b2.w);
        p1.z = pk2bf(b3.x,b3.y); p1.w = pk2bf(b3.z,b3.w);
        *reinterpret_cast<uint4*>(&Blds[n*36 + kq*8    ]) = p0;
        *reinterpret_cast<uint4*>(&Blds[n*36 + kq*8 + 4]) = p1;
    }
    __syncthreads();

    f32x4 acc[2][4];
    #pragma unroll
    for (int i=0;i<2;i++){
        #pragma unroll
        for (int j=0;j<4;j++){ acc[i][j][0]=0.f; acc[i][j][1]=0.f; acc[i][j][2]=0.f; acc[i][j][3]=0.f; }
    }
    #pragma unroll
    for (int ks = 0; ks < 2; ks++) {
        U8 au[2], bu[4];
        #pragma unroll
        for (int mt = 0; mt < 2; mt++)
            au[mt].u = *reinterpret_cast<const uint4*>(&Alds[(wv*32 + mt*16 + fr)*36 + ks*16 + kg*4]);
        #pragma unroll
        for (int nt = 0; nt < 4; nt++)
            bu[nt].u = *reinterpret_cast<const uint4*>(&Blds[(nt*16 + fr)*36 + ks*16 + kg*4]);
        #pragma unroll
        for (int mt = 0; mt < 2; mt++)
            #pragma unroll
            for (int nt = 0; nt < 4; nt++)
                acc[mt][nt] = __builtin_amdgcn_mfma_f32_16x16x32_bf16(
                    au[mt].v, bu[nt].v, acc[mt][nt], 0, 0, 0);
    }
    #pragma unroll
    for (int nt = 0; nt < 4; nt++) {
        #pragma unroll
        for (int mt = 0; mt < 2; mt++) {
            #pragma unroll
            for (int r = 0; r < 4; r++) {
                const int m = row0 + wv*32 + mt*16 + kg*4 + r;
                qsk[(size_t)m*DD + nt*16 + fr] = acc[mt][nt][r];
            }
        }
    }
}

// ---------------------------------------------------------------------------
// K2: content scores, MFMA bf16, f32 wc output.  (validated R9/R11)
// ---------------------------------------------------------------------------
__global__ __launch_bounds__(256) void k_scores(
    const float* __restrict__ q_s, const float* __restrict__ kk_, float* __restrict__ wc)
{
    const int bh = blockIdx.z;
    __shared__ __align__(16) unsigned Alds[128*36];
    __shared__ __align__(16) unsigned Blds[128*36];
    const int i0 = blockIdx.x * 128, j0 = blockIdx.y * 128;
    const int tid = threadIdx.x;
    const int wv  = tid >> 6, lane = tid & 63;
    const int wm  = wv & 1,  wn   = wv >> 1;
    const int fr  = lane & 15, kg = lane >> 4;

    {   // stage: row m = tid>>1, half kh = tid&1 -> 32 f32 = 16 words each
        const int m = tid >> 1, kh = tid & 1;
        const float4* ap = reinterpret_cast<const float4*>(q_s + ((size_t)bh*NN + i0 + m)*DD + kh*32);
        const float4* bp = reinterpret_cast<const float4*>(kk_ + ((size_t)bh*NN + j0 + m)*DD + kh*32);
        uint4 pa[4], pbq[4];
        pk32(ap, pa);
        pk32(bp, pbq);
        #pragma unroll
        for (int e = 0; e < 4; e++) {
            *reinterpret_cast<uint4*>(&Alds[m*36 + kh*16 + 4*e]) = pa[e];
            *reinterpret_cast<uint4*>(&Blds[m*36 + kh*16 + 4*e]) = pbq[e];
        }
    }
    __syncthreads();

    f32x4 acc[4][4];
    #pragma unroll
    for (int i=0;i<4;i++){
        #pragma unroll
        for (int j=0;j<4;j++){ acc[i][j][0]=0.f; acc[i][j][1]=0.f; acc[i][j][2]=0.f; acc[i][j][3]=0.f; }
    }
    #pragma unroll
    for (int ks = 0; ks < 2; ks++) {
        U8 au[4], bu[4];
        #pragma unroll
        for (int t = 0; t < 4; t++) {
            au[t].u = *reinterpret_cast<const uint4*>(&Alds[(wm*64 + t*16 + fr)*36 + ks*16 + kg*4]);
            bu[t].u = *reinterpret_cast<const uint4*>(&Blds[(wn*64 + t*16 + fr)*36 + ks*16 + kg*4]);
        }
        #pragma unroll
        for (int mt = 0; mt < 4; mt++)
            #pragma unroll
            for (int nt = 0; nt < 4; nt++)
                acc[mt][nt] = __builtin_amdgcn_mfma_f32_16x16x32_bf16(
                    au[mt].v, bu[nt].v, acc[mt][nt], 0, 0, 0);
    }
    #pragma unroll
    for (int nt = 0; nt < 4; nt++) {
        const int j = j0 + wn*64 + nt*16 + fr;
        #pragma unroll
        for (int mt = 0; mt < 4; mt++) {
            #pragma unroll
            for (int r = 0; r < 4; r++) {
                const int i = i0 + wm*64 + mt*16 + kg*4 + r;
                wc[((size_t)bh*NN + i)*NN + j] = acc[mt][nt][r];
            }
        }
    }
}

// ---------------------------------------------------------------------------
// K3: fused per-(b,i), MFMA scores + pagg.  R14: 768 threads (12 waves),
// 2-thread-per-row LN, 32-j score waves -> 6 waves/SIMD.
// wc stays f32 (R13 evidence: bf16 read hurt).
// ---------------------------------------------------------------------------
__global__ __launch_bounds__(768) void k_soft(
    const float* __restrict__ paths, const float* __restrict__ bias,
    const float* __restrict__ pg, const float* __restrict__ pb,
    const float* __restrict__ wc, const float* __restrict__ qsk,
    float* __restrict__ pagg, float* __restrict__ w_out)
{
    const int bi = blockIdx.x;
    const int b = bi / NN, i = bi % NN;
    __shared__ __align__(16) unsigned pLNT[32 * PSTR];
    __shared__ __align__(16) unsigned sw32[16 * SWS];
    __shared__ __align__(16) unsigned qskA[16 * 36];
    __shared__ float redM[12][16];
    __shared__ float redS[12][16];
    __shared__ float pgf[64], pbf[64];
    const int tid  = threadIdx.x;
    const int wv   = tid >> 6, lane = tid & 63;
    const int g    = lane >> 4, c = lane & 15;
    const int jbase = wv*32 + c;          // wave owns 32 j (2 nt tiles)

    // (1) paths half-row: row jrow = tid>>1, half hf = tid&1 (32 f32)
    const int jrow = tid >> 1, hf = tid & 1;
    float x[32];
    {
        const float4* src = reinterpret_cast<const float4*>(
            paths + ((size_t)bi * NN + jrow) * PHH + hf*32);
        #pragma unroll
        for (int t = 0; t < 8; t++) {
            float4 u = src[t];
            x[4*t]=u.x; x[4*t+1]=u.y; x[4*t+2]=u.z; x[4*t+3]=u.w;
        }
    }
    // (2) hoisted phase-2 operands (f32 wc)
    float wcv[2][4], biasj[2];
    #pragma unroll
    for (int nt = 0; nt < 2; nt++) {
        const int j = jbase + nt*16;
        biasj[nt] = bias[b*NN + j];
        #pragma unroll
        for (int r = 0; r < 4; r++) {
            const int h = g*4 + r;
            wcv[nt][r] = (h < HH) ? wc[((size_t)(b*HH + h)*NN + i)*NN + j] : 0.f;
        }
    }
    // (3) small LDS fills
    if (tid < 64) { pgf[tid] = pg[tid]; pbf[tid] = pb[tid]; }
    if (tid < 384) {   // fill qskA: h = tid>>5 (0..11), 2 ph per thread
        const int h = tid >> 5, t2 = tid & 31;
        const size_t r0 = ((size_t)(b*HH + h)*NN + i)*DD;
        const float q0 = qsk[r0 + 2*t2], q1 = qsk[r0 + 2*t2 + 1];
        qskA[h*36 + t2] = pk2bf(q0, q1);
        if (tid < 144) qskA[432 + tid] = 0u;
    }
    __syncthreads();

    {   // (4) LayerNorm, pair-split: mean/var combined via shfl_xor(1)
        float m0 = 0.f;
        #pragma unroll
        for (int t = 0; t < 32; t++) m0 += x[t];
        const float mo = __shfl_xor(m0, 1, 64);
        const float m = (m0 + mo) * (1.f/64.f);
        float v0 = 0.f;
        #pragma unroll
        for (int t = 0; t < 32; t++){ float d = x[t]-m; v0 = fmaf(d,d,v0); }
        const float vo = __shfl_xor(v0, 1, 64);
        const float rs = rsqrtf((v0+vo)*(1.f/64.f) + 1e-5f);
        #pragma unroll
        for (int t = 0; t < 16; t++){
            const int w = hf*16 + t;
            const int ph = hf*32 + 2*t;
            const float lo = (x[2*t  ]-m)*rs*pgf[ph  ] + pbf[ph  ];
            const float hi = (x[2*t+1]-m)*rs*pgf[ph+1] + pbf[ph+1];
            pLNT[w*PSTR + jrow] = pk2bf(lo, hi);
        }
    }
    __syncthreads();

    // ---- phase 2: scoresT via MFMA.  D[h = 4g+r][j = 32wv + 16nt + c]
    f32x4 sc[2];
    #pragma unroll
    for (int nt=0;nt<2;nt++){ sc[nt][0]=0.f; sc[nt][1]=0.f; sc[nt][2]=0.f; sc[nt][3]=0.f; }
    #pragma unroll
    for (int kh = 0; kh < 2; kh++) {
        U8 a; a.u = *reinterpret_cast<const uint4*>(&qskA[c*36 + kh*16 + g*4]);
        #pragma unroll
        for (int nt = 0; nt < 2; nt++) {
            const unsigned* pb_ = &pLNT[(kh*16 + g*4)*PSTR + jbase + nt*16];
            uint4 bw;
            bw.x = pb_[0]; bw.y = pb_[PSTR]; bw.z = pb_[2*PSTR]; bw.w = pb_[3*PSTR];
            U8 bb; bb.u = bw;
            sc[nt] = __builtin_amdgcn_mfma_f32_16x16x32_bf16(a.v, bb.v, sc[nt], 0, 0, 0);
        }
    }
    #pragma unroll
    for (int nt = 0; nt < 2; nt++)
        #pragma unroll
        for (int r = 0; r < 4; r++)
            sc[nt][r] += wcv[nt][r] + biasj[nt];

    // softmax: 16-lane-group reduce + cross-wave combine over 12 waves
    float e_[2][4], inv_[4];
    {
        float mr[4];
        #pragma unroll
        for (int r = 0; r < 4; r++) {
            float m2 = fmaxf(sc[0][r], sc[1][r]);
            #pragma unroll
            for (int o = 1; o <= 8; o <<= 1) m2 = fmaxf(m2, __shfl_xor(m2, o, 64));
            mr[r] = m2;
        }
        if (c == 0) {
            #pragma unroll
            for (int r = 0; r < 4; r++) redM[wv][g*4 + r] = mr[r];
        }
        __syncthreads();
        #pragma unroll
        for (int r = 0; r < 4; r++) {
            float Mv = redM[0][g*4 + r];
            #pragma unroll
            for (int w2 = 1; w2 < 12; w2++) Mv = fmaxf(Mv, redM[w2][g*4 + r]);
            float s2 = 0.f;
            #pragma unroll
            for (int nt = 0; nt < 2; nt++){ e_[nt][r] = __expf(sc[nt][r] - Mv); s2 += e_[nt][r]; }
            #pragma unroll
            for (int o = 1; o <= 8; o <<= 1) s2 += __shfl_xor(s2, o, 64);
            mr[r] = s2;
        }
        if (c == 0) {
            #pragma unroll
            for (int r = 0; r < 4; r++) redS[wv][g*4 + r] = mr[r];
        }
        __syncthreads();
        #pragma unroll
        for (int r = 0; r < 4; r++) {
            float Sv = redS[0][g*4 + r];
            #pragma unroll
            for (int w2 = 1; w2 < 12; w2++) Sv += redS[w2][g*4 + r];
            inv_[r] = 1.f / Sv;
        }
    }
    // w: store to global (h<12) + pack into sw (A-operand layout for pagg)
    #pragma unroll
    for (int nt = 0; nt < 2; nt++) {
        const int j = jbase + nt*16;
        #pragma unroll
        for (int r = 0; r < 4; r++) {
            const int h = g*4 + r;
            const float wgt = e_[nt][r] * inv_[r];
            if (h < HH) w_out[((size_t)(b*HH + h)*NN + i)*NN + j] = wgt;
            const float oth = __shfl_xor(wgt, 1, 64);
            if ((c & 1) == 0) sw32[h*SWS + (j >> 1)] = pk2bf(wgt, oth);
        }
    }
    __syncthreads();

    // ---- phase 3: pagg via MFMA.  waves 0..3: ph-tile = 16*wv.
    if (wv < 4) {
        f32x4 pa; pa[0]=0.f; pa[1]=0.f; pa[2]=0.f; pa[3]=0.f;
        const int prow = 8*wv + (c >> 1);
        const bool hi = (c & 1);
        #pragma unroll 4
        for (int kt = 0; kt < 12; kt++) {
            uint2 a0 = *reinterpret_cast<const uint2*>(&sw32[c*SWS + kt*16 + g*4]);
            uint2 a1 = *reinterpret_cast<const uint2*>(&sw32[c*SWS + kt*16 + g*4 + 2]);
            U8 af; af.u.x = a0.x; af.u.y = a0.y; af.u.z = a1.x; af.u.w = a1.y;
            const unsigned* pr = &pLNT[prow*PSTR + 32*kt + 8*g];
            uint2 w01 = *reinterpret_cast<const uint2*>(&pr[0]);
            uint2 w23 = *reinterpret_cast<const uint2*>(&pr[2]);
            uint2 w45 = *reinterpret_cast<const uint2*>(&pr[4]);
            uint2 w67 = *reinterpret_cast<const uint2*>(&pr[6]);
            uint4 bw;
            if (hi) {
                bw.x = (w01.x >> 16) | (w01.y & 0xffff0000u);
                bw.y = (w23.x >> 16) | (w23.y & 0xffff0000u);
                bw.z = (w45.x >> 16) | (w45.y & 0xffff0000u);
                bw.w = (w67.x >> 16) | (w67.y & 0xffff0000u);
            } else {
                bw.x = (w01.x & 0xffffu) | (w01.y << 16);
                bw.y = (w23.x & 0xffffu) | (w23.y << 16);
                bw.z = (w45.x & 0xffffu) | (w45.y << 16);
                bw.w = (w67.x & 0xffffu) | (w67.y << 16);
            }
            U8 bf_; bf_.u = bw;
            pa = __builtin_amdgcn_mfma_f32_16x16x32_bf16(af.v, bf_.v, pa, 0, 0, 0);
        }
        #pragma unroll
        for (int r = 0; r < 4; r++) {
            const int h = g*4 + r;
            if (h < HH)
                pagg[((size_t)(b*HH + h)*NN + i)*DD + 16*wv + c] = pa[r];
        }
    }
}

// ---------------------------------------------------------------------------
// K4: attn = w@v + pagg@Wsv + bsv, MFMA bf16.  (validated R9/R11)
// ---------------------------------------------------------------------------
__global__ __launch_bounds__(256) void k_av(
    const float* __restrict__ w, const float* __restrict__ v_,
    const float* __restrict__ pagg, const float* __restrict__ Wsv,
    const float* __restrict__ bsv, float* __restrict__ attn)
{
    const int bh = blockIdx.y;
    const int b = bh / HH, h = bh % HH;
    const int i0 = blockIdx.x * 128;
    __shared__ __align__(16) unsigned Alds[128*36];
    __shared__ __align__(16) unsigned Blds[64*36];
    const int tid = threadIdx.x;
    const int wv  = tid >> 6, lane = tid & 63;
    const int fr  = lane & 15, kg = lane >> 4;

    f32x4 acc[2][4];
    #pragma unroll
    for (int i=0;i<2;i++){
        #pragma unroll
        for (int j=0;j<4;j++){ acc[i][j][0]=0.f; acc[i][j][1]=0.f; acc[i][j][2]=0.f; acc[i][j][3]=0.f; }
    }

    for (int step = 0; step < 7; step++) {
        const int j0 = step * 64;
        {   // stage A rows: w (steps 0-5) or pagg (step 6); 32 f32/thread
            const int m = tid >> 1, kh = tid & 1;
            const float4* ap = (step < 6)
                ? reinterpret_cast<const float4*>(w    + ((size_t)bh*NN + i0 + m)*NN  + j0 + kh*32)
                : reinterpret_cast<const float4*>(pagg + ((size_t)bh*NN + i0 + m)*PHH + kh*32);
            uint4 pa[4];
            pk32(ap, pa);
            #pragma unroll
            for (int e = 0; e < 4; e++)
                *reinterpret_cast<uint4*>(&Alds[m*36 + kh*16 + 4*e]) = pa[e];
        }
        {   // stage B^T: v (steps 0-5) or Wsv (step 6); column reads
            const int d = tid & 63, kq = tid >> 6;
            const float* vp = (step < 6)
                ? (v_  + ((size_t)bh*NN + j0 + kq*16)*DD + d)
                : (Wsv + (size_t)(kq*16)*DD + d);
            float x[16];
            #pragma unroll
            for (int t = 0; t < 16; t++) x[t] = vp[(size_t)t*DD];
            uint4 p0,p1;
            p0.x=pk2bf(x[0],x[1]);   p0.y=pk2bf(x[2],x[3]);
            p0.z=pk2bf(x[4],x[5]);   p0.w=pk2bf(x[6],x[7]);
            p1.x=pk2bf(x[8],x[9]);   p1.y=pk2bf(x[10],x[11]);
            p1.z=pk2bf(x[12],x[13]); p1.w=pk2bf(x[14],x[15]);
            *reinterpret_cast<uint4*>(&Blds[d*36 + kq*8    ]) = p0;
            *reinterpret_cast<uint4*>(&Blds[d*36 + kq*8 + 4]) = p1;
        }
        __syncthreads();
        #pragma unroll
        for (int ks = 0; ks < 2; ks++) {
            U8 au[2], bu[4];
            #pragma unroll
            for (int mt = 0; mt < 2; mt++)
                au[mt].u = *reinterpret_cast<const uint4*>(&Alds[(wv*32 + mt*16 + fr)*36 + ks*16 + kg*4]);
            #pragma unroll
            for (int nt = 0; nt < 4; nt++)
                bu[nt].u = *reinterpret_cast<const uint4*>(&Blds[(nt*16 + fr)*36 + ks*16 + kg*4]);
            #pragma unroll
            for (int mt = 0; mt < 2; mt++)
                #pragma unroll
                for (int nt = 0; nt < 4; nt++)
                    acc[mt][nt] = __builtin_amdgcn_mfma_f32_16x16x32_bf16(
                        au[mt].v, bu[nt].v, acc[mt][nt], 0, 0, 0);
        }
        __syncthreads();
    }
    #pragma unroll
    for (int nt = 0; nt < 4; nt++) {
        const int d = nt*16 + fr;
        const float bv_ = bsv[d];
        #pragma unroll
        for (int mt = 0; mt < 2; mt++) {
            #pragma unroll
            for (int r = 0; r < 4; r++) {
                const int i = i0 + wv*32 + mt*16 + kg*4 + r;
                attn[((size_t)b*NN + i)*HSZ + h*DD + d] = acc[mt][nt][r] + bv_;
            }
        }
    }
}

// ---------------------------------------------------------------------------
// K5a: tres = nodes + relu(attn @ Wo + bo)   -- MFMA (validated R7)
// ---------------------------------------------------------------------------
__global__ __launch_bounds__(256) void k_proj(
    const float* __restrict__ attn, const float* __restrict__ Wo,
    const float* __restrict__ bo, const float* __restrict__ nodes,
    float* __restrict__ tres)
{
    __shared__ __align__(16) unsigned Alds[128*20];
    __shared__ __align__(16) unsigned Blds[128*20];

    const int row0 = blockIdx.x * 128;
    const int col0 = blockIdx.y * 128;
    const int tid  = threadIdx.x;
    const int wv   = tid >> 6, lane = tid & 63;
    const int wm   = wv & 1,  wn   = wv >> 1;
    const int fr   = lane & 15, kg = lane >> 4;

    f32x4 acc[4][4];
    #pragma unroll
    for (int i=0;i<4;i++){
        #pragma unroll
        for (int j=0;j<4;j++){ acc[i][j][0]=0.f; acc[i][j][1]=0.f; acc[i][j][2]=0.f; acc[i][j][3]=0.f; }
    }

    for (int k0 = 0; k0 < HSZ; k0 += 32) {
        {
            const int m = tid >> 1, kh = tid & 1;
            const float4* ap = reinterpret_cast<const float4*>(attn + (size_t)(row0 + m)*HSZ + k0 + kh*16);
            float4 a0 = ap[0], a1 = ap[1], a2 = ap[2], a3 = ap[3];
            uint4 p0, p1;
            p0.x = pk2bf(a0.x,a0.y); p0.y = pk2bf(a0.z,a0.w);
            p0.z = pk2bf(a1.x,a1.y); p0.w = pk2bf(a1.z,a1.w);
            p1.x = pk2bf(a2.x,a2.y); p1.y = pk2bf(a2.z,a2.w);
            p1.z = pk2bf(a3.x,a3.y); p1.w = pk2bf(a3.z,a3.w);
            *reinterpret_cast<uint4*>(&Alds[m*20 + kh*8    ]) = p0;
            *reinterpret_cast<uint4*>(&Alds[m*20 + kh*8 + 4]) = p1;
        }
        {
            const int n = tid & 127, kq = tid >> 7;
            const float* wp = Wo + (size_t)(k0 + kq*16)*HSZ + col0 + n;
            float x[16];
            #pragma unroll
            for (int j = 0; j < 16; j++) x[j] = wp[(size_t)j*HSZ];
            uint4 p0, p1;
            p0.x = pk2bf(x[0],x[1]);   p0.y = pk2bf(x[2],x[3]);
            p0.z = pk2bf(x[4],x[5]);   p0.w = pk2bf(x[6],x[7]);
            p1.x = pk2bf(x[8],x[9]);   p1.y = pk2bf(x[10],x[11]);
            p1.z = pk2bf(x[12],x[13]); p1.w = pk2bf(x[14],x[15]);
            *reinterpret_cast<uint4*>(&Blds[n*20 + kq*8    ]) = p0;
            *reinterpret_cast<uint4*>(&Blds[n*20 + kq*8 + 4]) = p1;
        }
        __syncthreads();
        U8 au[4], bu[4];
        #pragma unroll
        for (int t = 0; t < 4; t++) {
            au[t].u = *reinterpret_cast<const uint4*>(&Alds[(wm*64 + t*16 + fr)*20 + kg*4]);
            bu[t].u = *reinterpret_cast<const uint4*>(&Blds[(wn*64 + t*16 + fr)*20 + kg*4]);
        }
        #pragma unroll
        for (int mt = 0; mt < 4; mt++)
            #pragma unroll
            for (int nt = 0; nt < 4; nt++)
                acc[mt][nt] = __builtin_amdgcn_mfma_f32_16x16x32_bf16(
                    au[mt].v, bu[nt].v, acc[mt][nt], 0, 0, 0);
        __syncthreads();
    }
    #pragma unroll
    for (int nt = 0; nt < 4; nt++) {
        const int col = col0 + wn*64 + nt*16 + fr;
        const float bov = bo[col];
        #pragma unroll
        for (int mt = 0; mt < 4; mt++) {
            #pragma unroll
            for (int r = 0; r < 4; r++) {
                const int m = row0 + wm*64 + mt*16 + kg*4 + r;
                const float val = fmaxf(acc[mt][nt][r] + bov, 0.f) + nodes[(size_t)m*HSZ + col];
                tres[(size_t)m*HSZ + col] = val;
            }
        }
    }
}

// ---------------------------------------------------------------------------
// K5b: row LayerNorm, 1 wave per row, 4 rows/block.  (validated R11)
// ---------------------------------------------------------------------------
__global__ __launch_bounds__(256) void k_ln(
    const float* __restrict__ tres, const float* __restrict__ g,
    const float* __restrict__ bta, float* __restrict__ out0)
{
    const int row  = blockIdx.x * 4 + (threadIdx.x >> 6);
    const int lane = threadIdx.x & 63;
    const float4* x4 = reinterpret_cast<const float4*>(tres + (size_t)row * HSZ);
    float4 v[3];
    #pragma unroll
    for (int t = 0; t < 3; t++) v[t] = x4[lane + t*64];
    float s = 0.f;
    #pragma unroll
    for (int t = 0; t < 3; t++) s += v[t].x + v[t].y + v[t].z + v[t].w;
    #pragma unroll
    for (int o = 32; o > 0; o >>= 1) s += __shfl_xor(s, o, 64);
    const float m = s * (1.f/768.f);
    float vs = 0.f;
    #pragma unroll
    for (int t = 0; t < 3; t++) {
        float a = v[t].x-m, b = v[t].y-m, c = v[t].z-m, d = v[t].w-m;
        vs += a*a + b*b + c*c + d*d;
    }
    #pragma unroll
    for (int o = 32; o > 0; o >>= 1) vs += __shfl_xor(vs, o, 64);
    const float rs = rsqrtf(vs * (1.f/768.f) + 1e-5f);
    const float4* g4 = reinterpret_cast<const float4*>(g);
    const float4* b4 = reinterpret_cast<const float4*>(bta);
    float4* o4 = reinterpret_cast<float4*>(out0 + (size_t)row * HSZ);
    #pragma unroll
    for (int t = 0; t < 3; t++) {
        const int idx = lane + t*64;
        float4 gg = g4[idx], bb = b4[idx], o;
        o.x = (v[t].x-m)*rs*gg.x + bb.x;
        o.y = (v[t].y-m)*rs*gg.y + bb.y;
        o.z = (v[t].z-m)*rs*gg.z + bb.z;
        o.w = (v[t].w-m)*rs*gg.w + bb.w;
        o4[idx] = o;
    }
}

// ---------------------------------------------------------------------------
extern "C" void kernel_launch(void* const* d_in, const int* in_sizes, int n_in,
                              void* d_out, int out_size, void* d_ws, size_t ws_size,
                              hipStream_t stream)
{
    (void)in_sizes; (void)n_in; (void)out_size; (void)ws_size;
    const float* nodes = (const float*)d_in[0];
    const float* bias  = (const float*)d_in[1];
    const float* paths = (const float*)d_in[2];
    const float* Wq = (const float*)d_in[3];
    const float* bq = (const float*)d_in[4];
    const float* Wk = (const float*)d_in[5];
    const float* bk = (const float*)d_in[6];
    const float* Wv = (const float*)d_in[7];
    const float* bv = (const float*)d_in[8];
    const float* Wsk= (const float*)d_in[9];
    const float* Wsv= (const float*)d_in[11];
    const float* bsv= (const float*)d_in[12];
    const float* Wo = (const float*)d_in[13];
    const float* bo = (const float*)d_in[14];
    const float* lng= (const float*)d_in[15];
    const float* lnb= (const float*)d_in[16];
    const float* plg= (const float*)d_in[17];
    const float* plb= (const float*)d_in[18];

    // ws layout (f32 slots), lifetime reuse (R11 layout):
    float* ws   = (float*)d_ws;
    float* q_s  = ws;
    float* kbuf = ws + 2359296;
    float* vbuf = ws + 4718592;
    float* qsk  = ws + 7077888;
    float* wc   = ws + 9474048;
    float* attn = q_s;
    float* pagg = kbuf;
    float* tres = wc;

    float* out0 = (float*)d_out;
    float* wout = out0 + (size_t)BB*NN*HSZ;

    hipLaunchKernelGGL(k_qkv,    dim3(24,6,3), dim3(256), 0, stream,
                       nodes, Wq,bq, Wk,bk, Wv,bv, q_s, kbuf, vbuf);
    hipLaunchKernelGGL(k_qsk,    dim3(288),    dim3(256), 0, stream,
                       q_s, Wsk, qsk);
    hipLaunchKernelGGL(k_scores, dim3(3,3,96), dim3(256), 0, stream,
                       q_s, kbuf, wc);
    hipLaunchKernelGGL(k_soft,   dim3(3072),   dim3(768), 0, stream,
                       paths, bias, plg, plb, wc, qsk, pagg, wout);
    hipLaunchKernelGGL(k_av,     dim3(3,96),   dim3(256), 0, stream,
                       wout, vbuf, pagg, Wsv, bsv, attn);
    hipLaunchKernelGGL(k_proj,   dim3(24,6),   dim3(256), 0, stream,
                       attn, Wo, bo, nodes, tres);
    hipLaunchKernelGGL(k_ln,     dim3(768),    dim3(256), 0, stream,
                       tres, lng, lnb, out0);
}